// Round 1
// baseline (665.626 us; speedup 1.0000x reference)
//
#include <hip/hip_runtime.h>
#include <hip/hip_bf16.h>

// LoRA multi-head self-attention fwd, fp32 baseline.
// B=4, N=1024, D=768, H=12, hd=64, rank=8, SCALING=SCALE=0.125
//
// Pipeline:
//   1. combine_w : Wcat[2304][768] = qkv_w with q/k base weights folded in; bcat likewise
//   2. lora_xa   : XA[4096][16] = [x@q_A.T | x@k_A.T]
//   3. gemm<0>   : QKV = x@Wcat.T + bcat + lora-epilogue, scattered to [B][H][N][hd]
//   4. attn_k    : flash attention per (bh, 64-row q block) -> AO[4096][768]
//   5. gemm<1>   : out = AO@proj_w.T + proj_b
//
// ws requirement: 57,680,896 bytes (fp32). All ws regions fully written before read.

#define M_TOT 4096

// ---- workspace layout (float offsets) ----
constexpr size_t OFF_W  = 0;                          // 2304*768
constexpr size_t OFF_B  = OFF_W  + (size_t)2304*768;  // 2304
constexpr size_t OFF_XA = OFF_B  + 2304;              // 4096*16
constexpr size_t OFF_Q  = OFF_XA + (size_t)4096*16;   // 4096*768
constexpr size_t OFF_K  = OFF_Q  + (size_t)4096*768;
constexpr size_t OFF_V  = OFF_K  + (size_t)4096*768;
constexpr size_t OFF_AO = OFF_V  + (size_t)4096*768;

// ---------------- kernel 1: fold base weights into qkv weights ----------------
__global__ __launch_bounds__(256)
void combine_w(const float* __restrict__ qkv_w, const float* __restrict__ qkv_b,
               const float* __restrict__ qw, const float* __restrict__ qb,
               const float* __restrict__ kw, const float* __restrict__ kb,
               float* __restrict__ Wcat, float* __restrict__ bcat) {
    const int idx = blockIdx.x * 256 + threadIdx.x;
    const int total = 2304 * 768;
    if (idx < total) {
        const int n = idx / 768;
        const int k = idx - n * 768;
        float v = qkv_w[idx];
        if (n < 768)        v += qw[n * 768 + k];
        else if (n < 1536)  v += kw[(n - 768) * 768 + k];
        Wcat[idx] = v;
    } else if (idx < total + 2304) {
        const int n = idx - total;
        float v = qkv_b[n];
        if (n < 768)        v += qb[n];
        else if (n < 1536)  v += kb[n - 768];
        bcat[n] = v;
    }
}

// ---------------- kernel 2: XA = [x@q_A.T | x@k_A.T]  (rank 8 each) ----------------
__global__ __launch_bounds__(256)
void lora_xa(const float* __restrict__ x, const float* __restrict__ qA,
             const float* __restrict__ kA, float* __restrict__ XA) {
    __shared__ float xs[768];
    const int m = blockIdx.x;
    const float* xr = x + (size_t)m * 768;
    for (int i = threadIdx.x; i < 768; i += 256) xs[i] = xr[i];
    __syncthreads();
    const int j = threadIdx.x >> 4;   // 0..15 output col
    const int l = threadIdx.x & 15;   // partial lane
    const float* Arow = (j < 8) ? (qA + j * 768) : (kA + (j - 8) * 768);
    float acc = 0.f;
    for (int k = l; k < 768; k += 16) acc += xs[k] * Arow[k];
    acc += __shfl_xor(acc, 1);
    acc += __shfl_xor(acc, 2);
    acc += __shfl_xor(acc, 4);
    acc += __shfl_xor(acc, 8);
    if (l == 0) XA[m * 16 + j] = acc;
}

// ---------------- kernels 3 & 5: tiled fp32 GEMM, C = A @ Bw.T ----------------
// MODE 0: Bw=Wcat[2304][768]; epilogue adds bcat + LoRA dot, scatters to Q/K/V [B][H][N][hd]
// MODE 1: Bw=proj_w[768][768]; epilogue adds bias, writes Co[m][n]
template<int BM, int BN, int TM, int TN, int MODE>
__global__ __launch_bounds__(256)
void gemm_k(const float* __restrict__ A, const float* __restrict__ Bw,
            const float* __restrict__ bias, const float* __restrict__ XA,
            const float* __restrict__ qB, const float* __restrict__ kB,
            float* __restrict__ Oq, float* __restrict__ Ok, float* __restrict__ Ov,
            float* __restrict__ Co) {
    __shared__ float As[16][BM + 4];   // k-major, +4 pad
    __shared__ float Bs[16][BN + 4];
    const int t  = threadIdx.x;
    const int tx = t & 15, ty = t >> 4;
    const int n0 = blockIdx.x * BN, m0 = blockIdx.y * BM;

    float acc[TM][TN];
#pragma unroll
    for (int i = 0; i < TM; ++i)
#pragma unroll
        for (int j = 0; j < TN; ++j) acc[i][j] = 0.f;

    for (int s = 0; s < 48; ++s) {           // K = 768, BK = 16
        const int k0 = s * 16;
#pragma unroll
        for (int i = 0; i < BM / 64; ++i) {  // stage A tile (transposed into LDS)
            const int cid = t + i * 256;
            const int row = cid >> 2, k4 = (cid & 3) * 4;
            const float4 v = *(const float4*)(A + (size_t)(m0 + row) * 768 + k0 + k4);
            As[k4 + 0][row] = v.x; As[k4 + 1][row] = v.y;
            As[k4 + 2][row] = v.z; As[k4 + 3][row] = v.w;
        }
#pragma unroll
        for (int i = 0; i < BN / 64; ++i) {  // stage B tile
            const int cid = t + i * 256;
            const int row = cid >> 2, k4 = (cid & 3) * 4;
            const float4 v = *(const float4*)(Bw + (size_t)(n0 + row) * 768 + k0 + k4);
            Bs[k4 + 0][row] = v.x; Bs[k4 + 1][row] = v.y;
            Bs[k4 + 2][row] = v.z; Bs[k4 + 3][row] = v.w;
        }
        __syncthreads();
#pragma unroll
        for (int kk = 0; kk < 16; ++kk) {
            float a[TM], b[TN];
#pragma unroll
            for (int i4 = 0; i4 < TM / 4; ++i4) {
                const float4 v = *(const float4*)&As[kk][ty * TM + i4 * 4];
                a[i4 * 4 + 0] = v.x; a[i4 * 4 + 1] = v.y;
                a[i4 * 4 + 2] = v.z; a[i4 * 4 + 3] = v.w;
            }
#pragma unroll
            for (int j4 = 0; j4 < TN / 4; ++j4) {
                const float4 v = *(const float4*)&Bs[kk][tx * TN + j4 * 4];
                b[j4 * 4 + 0] = v.x; b[j4 * 4 + 1] = v.y;
                b[j4 * 4 + 2] = v.z; b[j4 * 4 + 3] = v.w;
            }
#pragma unroll
            for (int i = 0; i < TM; ++i)
#pragma unroll
                for (int j = 0; j < TN; ++j)
                    acc[i][j] = fmaf(a[i], b[j], acc[i][j]);
        }
        __syncthreads();
    }

    if (MODE == 0) {
#pragma unroll
        for (int i = 0; i < TM; ++i) {
            const int m = m0 + ty * TM + i;
            float xr[16];
#pragma unroll
            for (int u = 0; u < 4; ++u) {
                const float4 v = *(const float4*)(XA + m * 16 + u * 4);
                xr[u * 4 + 0] = v.x; xr[u * 4 + 1] = v.y;
                xr[u * 4 + 2] = v.z; xr[u * 4 + 3] = v.w;
            }
            const int b_ = m >> 10, nn = m & 1023;
#pragma unroll
            for (int j = 0; j < TN; ++j) {
                const int n = n0 + tx * TN + j;
                float c = acc[i][j] + bias[n];
                const int sel = (n >= 1536) ? 2 : (n >= 768 ? 1 : 0);
                const int jj = n - sel * 768;
                if (sel == 0) {
                    const float* bw = qB + jj * 8;
                    float lo = 0.f;
#pragma unroll
                    for (int r = 0; r < 8; ++r) lo += xr[r] * bw[r];
                    c += 0.125f * lo;
                } else if (sel == 1) {
                    const float* bw = kB + jj * 8;
                    float lo = 0.f;
#pragma unroll
                    for (int r = 0; r < 8; ++r) lo += xr[8 + r] * bw[r];
                    c += 0.125f * lo;
                }
                const int h = jj >> 6, d = jj & 63;
                float* dst = (sel == 0) ? Oq : (sel == 1 ? Ok : Ov);
                dst[(((size_t)(b_ * 12 + h)) * 1024 + nn) * 64 + d] = c;
            }
        }
    } else {
#pragma unroll
        for (int i = 0; i < TM; ++i) {
            const int m = m0 + ty * TM + i;
#pragma unroll
            for (int j = 0; j < TN; ++j) {
                const int n = n0 + tx * TN + j;
                Co[(size_t)m * 768 + n] = acc[i][j] + bias[n];
            }
        }
    }
}

// ---------------- kernel 4: flash attention (fp32) ----------------
// block = 256 threads, one (bh, 64-row q block). KB tile = 64. softmax scale 0.125.
// Thread (tx=t&15, ty=t>>4): S rows ty+16*ii, S cols tx+16*jj, O cols tx*4+jj.
__global__ __launch_bounds__(256)
void attn_k(const float* __restrict__ Q, const float* __restrict__ K,
            const float* __restrict__ V, float* __restrict__ AO) {
    __shared__ float Qs[64][68];
    __shared__ float KP[64][68];   // K tile, reused as P tile
    __shared__ float Vs[64][68];
    const int t  = threadIdx.x;
    const int tx = t & 15, ty = t >> 4;
    const int qb = blockIdx.x, bh = blockIdx.y;
    const float* Qp = Q + (size_t)bh * (1024 * 64);
    const float* Kp = K + (size_t)bh * (1024 * 64);
    const float* Vp = V + (size_t)bh * (1024 * 64);

#pragma unroll
    for (int i = 0; i < 4; ++i) {            // stage Q tile
        const int cid = t + i * 256;
        const int row = cid >> 4, c4 = (cid & 15) * 4;
        *(float4*)&Qs[row][c4] = *(const float4*)&Qp[(size_t)(qb * 64 + row) * 64 + c4];
    }

    float O[4][4], mrun[4], lrun[4];
#pragma unroll
    for (int ii = 0; ii < 4; ++ii) {
        mrun[ii] = -1e30f; lrun[ii] = 0.f;
#pragma unroll
        for (int jj = 0; jj < 4; ++jj) O[ii][jj] = 0.f;
    }

    for (int kb = 0; kb < 16; ++kb) {
        __syncthreads();                      // prev PV done; safe to restage
#pragma unroll
        for (int i = 0; i < 4; ++i) {
            const int cid = t + i * 256;
            const int row = cid >> 4, c4 = (cid & 15) * 4;
            *(float4*)&KP[row][c4] = *(const float4*)&Kp[(size_t)(kb * 64 + row) * 64 + c4];
            *(float4*)&Vs[row][c4] = *(const float4*)&Vp[(size_t)(kb * 64 + row) * 64 + c4];
        }
        __syncthreads();

        float s[4][4];
#pragma unroll
        for (int ii = 0; ii < 4; ++ii)
#pragma unroll
            for (int jj = 0; jj < 4; ++jj) s[ii][jj] = 0.f;
#pragma unroll
        for (int k4 = 0; k4 < 16; ++k4) {     // S = Q @ K^T
            float4 qv[4], kv[4];
#pragma unroll
            for (int ii = 0; ii < 4; ++ii) qv[ii] = *(const float4*)&Qs[ty + 16 * ii][k4 * 4];
#pragma unroll
            for (int jj = 0; jj < 4; ++jj) kv[jj] = *(const float4*)&KP[tx + 16 * jj][k4 * 4];
#pragma unroll
            for (int ii = 0; ii < 4; ++ii)
#pragma unroll
                for (int jj = 0; jj < 4; ++jj)
                    s[ii][jj] += qv[ii].x * kv[jj].x + qv[ii].y * kv[jj].y
                               + qv[ii].z * kv[jj].z + qv[ii].w * kv[jj].w;
        }

        float p[4][4];
#pragma unroll
        for (int ii = 0; ii < 4; ++ii) {      // online softmax (row stats over 16 tx lanes)
#pragma unroll
            for (int jj = 0; jj < 4; ++jj) s[ii][jj] *= 0.125f;
            float mx = fmaxf(fmaxf(s[ii][0], s[ii][1]), fmaxf(s[ii][2], s[ii][3]));
            mx = fmaxf(mx, __shfl_xor(mx, 1));
            mx = fmaxf(mx, __shfl_xor(mx, 2));
            mx = fmaxf(mx, __shfl_xor(mx, 4));
            mx = fmaxf(mx, __shfl_xor(mx, 8));
            const float mn = fmaxf(mrun[ii], mx);
            const float alpha = __expf(mrun[ii] - mn);
            mrun[ii] = mn;
            float rs = 0.f;
#pragma unroll
            for (int jj = 0; jj < 4; ++jj) { p[ii][jj] = __expf(s[ii][jj] - mn); rs += p[ii][jj]; }
            rs += __shfl_xor(rs, 1);
            rs += __shfl_xor(rs, 2);
            rs += __shfl_xor(rs, 4);
            rs += __shfl_xor(rs, 8);
            lrun[ii] = lrun[ii] * alpha + rs;
#pragma unroll
            for (int jj = 0; jj < 4; ++jj) O[ii][jj] *= alpha;
        }

        __syncthreads();                      // all K reads done; KP becomes P
#pragma unroll
        for (int ii = 0; ii < 4; ++ii)
#pragma unroll
            for (int jj = 0; jj < 4; ++jj)
                KP[ty + 16 * ii][tx + 16 * jj] = p[ii][jj];
        __syncthreads();

#pragma unroll
        for (int c4 = 0; c4 < 16; ++c4) {     // O += P @ V
            float4 pv[4];
#pragma unroll
            for (int ii = 0; ii < 4; ++ii) pv[ii] = *(const float4*)&KP[ty + 16 * ii][c4 * 4];
#pragma unroll
            for (int q = 0; q < 4; ++q) {
                const float4 vv = *(const float4*)&Vs[c4 * 4 + q][tx * 4];
#pragma unroll
                for (int ii = 0; ii < 4; ++ii) {
                    const float pp = (q == 0) ? pv[ii].x : (q == 1) ? pv[ii].y
                                   : (q == 2) ? pv[ii].z : pv[ii].w;
                    O[ii][0] += pp * vv.x; O[ii][1] += pp * vv.y;
                    O[ii][2] += pp * vv.z; O[ii][3] += pp * vv.w;
                }
            }
        }
    }

    const int b_ = bh / 12, h = bh % 12;      // AO[b*1024+n][h*64 + d]
#pragma unroll
    for (int ii = 0; ii < 4; ++ii) {
        const float inv = 1.f / lrun[ii];
        const int n = qb * 64 + ty + 16 * ii;
        const size_t off = ((size_t)(b_ * 1024 + n)) * 768 + h * 64 + tx * 4;
        float4 o; o.x = O[ii][0] * inv; o.y = O[ii][1] * inv;
                  o.z = O[ii][2] * inv; o.w = O[ii][3] * inv;
        *(float4*)&AO[off] = o;
    }
}

// ---------------- launcher ----------------
extern "C" void kernel_launch(void* const* d_in, const int* in_sizes, int n_in,
                              void* d_out, int out_size, void* d_ws, size_t ws_size,
                              hipStream_t stream) {
    (void)in_sizes; (void)n_in; (void)out_size; (void)ws_size;
    const float* x      = (const float*)d_in[0];
    const float* qkv_w  = (const float*)d_in[1];
    const float* qkv_b  = (const float*)d_in[2];
    const float* q_bw   = (const float*)d_in[3];
    const float* q_bb   = (const float*)d_in[4];
    const float* q_A    = (const float*)d_in[5];
    const float* q_B    = (const float*)d_in[6];
    const float* k_bw   = (const float*)d_in[7];
    const float* k_bb   = (const float*)d_in[8];
    const float* k_A    = (const float*)d_in[9];
    const float* k_B    = (const float*)d_in[10];
    const float* proj_w = (const float*)d_in[11];
    const float* proj_b = (const float*)d_in[12];
    float* out = (float*)d_out;
    float* ws  = (float*)d_ws;

    float* Wcat = ws + OFF_W;
    float* bcat = ws + OFF_B;
    float* XA   = ws + OFF_XA;
    float* Qw   = ws + OFF_Q;
    float* Kw   = ws + OFF_K;
    float* Vw   = ws + OFF_V;
    float* AO   = ws + OFF_AO;

    combine_w<<<dim3(6930), dim3(256), 0, stream>>>(qkv_w, qkv_b, q_bw, q_bb, k_bw, k_bb, Wcat, bcat);
    lora_xa<<<dim3(4096), dim3(256), 0, stream>>>(x, q_A, k_A, XA);
    gemm_k<128, 128, 8, 8, 0><<<dim3(18, 32), dim3(256), 0, stream>>>(
        x, Wcat, bcat, XA, q_B, k_B, Qw, Kw, Vw, nullptr);
    attn_k<<<dim3(16, 48), dim3(256), 0, stream>>>(Qw, Kw, Vw, AO);
    gemm_k<64, 64, 4, 4, 1><<<dim3(12, 64), dim3(256), 0, stream>>>(
        AO, proj_w, proj_b, nullptr, nullptr, nullptr, nullptr, nullptr, nullptr, out);
}

// Round 2
// 174.892 us; speedup vs baseline: 3.8059x; 3.8059x over previous
//
#include <hip/hip_runtime.h>
#include <hip/hip_bf16.h>

// LoRA MHSA fwd, fp16-MFMA version. B=4,N=1024,D=768,H=12,hd=64,r=8,SCALE=SCALING=0.125
//
// prep     : Wh=fp16(qkv_w + folded q/k base), Ph=fp16(proj_w), bcat=f32 bias
// lora_xa  : XA[4096][16] f32 = [x@qA.T | x@kA.T]; Xh = fp16(x)
// gemm_h<0>: QKV = Xh@Wh.T (+bias+LoRA) -> Qh,Kh,Vh fp16 [bh][n][64]
// vt_k     : Vt[bh][64][1024] = transpose(Vh)
// attn_h   : flash attn (MFMA QK^T + PV, f32 softmax) -> AOh fp16 [4096][768]
// gemm_h<1>: out = AOh@Ph.T + proj_b (f32)

typedef _Float16 half8 __attribute__((ext_vector_type(8)));
typedef float f32x4 __attribute__((ext_vector_type(4)));

typedef __attribute__((address_space(3))) unsigned int lds_u32;
typedef __attribute__((address_space(1))) const unsigned int glob_u32;

__device__ __forceinline__ void glds16(const void* g, void* l) {
    __builtin_amdgcn_global_load_lds((glob_u32*)g, (lds_u32*)l, 16, 0, 0);
}

// ---- ws layout (byte offsets) ----
constexpr size_t OFF_WH  = 0;                         // 2304*768 f16
constexpr size_t OFF_PH  = OFF_WH  + 2304*768*2;      // 768*768 f16
constexpr size_t OFF_BC  = OFF_PH  + 768*768*2;       // 2304 f32
constexpr size_t OFF_XA  = OFF_BC  + 2304*4;          // 4096*16 f32
constexpr size_t OFF_XH  = OFF_XA  + 4096*16*4;       // 4096*768 f16
constexpr size_t OFF_QH  = OFF_XH  + (size_t)4096*768*2;
constexpr size_t OFF_KH  = OFF_QH  + (size_t)4096*768*2;
constexpr size_t OFF_VH  = OFF_KH  + (size_t)4096*768*2;
constexpr size_t OFF_VT  = OFF_VH  + (size_t)4096*768*2;
constexpr size_t OFF_AO  = OFF_VT  + (size_t)4096*768*2;

// ---------------- prep: fold + fp16 convert weights ----------------
__global__ __launch_bounds__(256)
void prep(const float* __restrict__ qkv_w, const float* __restrict__ qkv_b,
          const float* __restrict__ qw, const float* __restrict__ qb,
          const float* __restrict__ kw, const float* __restrict__ kb,
          const float* __restrict__ proj_w,
          _Float16* __restrict__ Wh, _Float16* __restrict__ Ph, float* __restrict__ bcat) {
    const int idx = blockIdx.x * 256 + threadIdx.x;
    const int NW = 2304 * 768, NP = 768 * 768;
    if (idx < NW) {
        const int n = idx / 768, k = idx - n * 768;
        float v = qkv_w[idx];
        if (n < 768)        v += qw[n * 768 + k];
        else if (n < 1536)  v += kw[(n - 768) * 768 + k];
        Wh[idx] = (_Float16)v;
    } else if (idx < NW + NP) {
        Ph[idx - NW] = (_Float16)proj_w[idx - NW];
    } else if (idx < NW + NP + 2304) {
        const int n = idx - NW - NP;
        float v = qkv_b[n];
        if (n < 768)        v += qb[n];
        else if (n < 1536)  v += kb[n - 768];
        bcat[n] = v;
    }
}

// ---------------- lora_xa: XA = [x@qA.T | x@kA.T], Xh = fp16(x) ----------------
__global__ __launch_bounds__(256)
void lora_xa(const float* __restrict__ x, const float* __restrict__ qA,
             const float* __restrict__ kA, float* __restrict__ XA, _Float16* __restrict__ Xh) {
    __shared__ float xs[768];
    const int m = blockIdx.x;
    const float* xr = x + (size_t)m * 768;
    for (int i = threadIdx.x; i < 768; i += 256) {
        float v = xr[i]; xs[i] = v; Xh[(size_t)m * 768 + i] = (_Float16)v;
    }
    __syncthreads();
    const int j = threadIdx.x >> 4, l = threadIdx.x & 15;
    const float* Arow = (j < 8) ? (qA + j * 768) : (kA + (j - 8) * 768);
    float acc = 0.f;
    for (int k = l; k < 768; k += 16) acc += xs[k] * Arow[k];
    acc += __shfl_xor(acc, 1); acc += __shfl_xor(acc, 2);
    acc += __shfl_xor(acc, 4); acc += __shfl_xor(acc, 8);
    if (l == 0) XA[m * 16 + j] = acc;
}

// ---------------- fp16 MFMA GEMM: C = A @ Bw.T ----------------
// 128x128 tile, BK=32, 4 waves (2x2), each wave 64x64 = 4x4 frags of 16x16x32.
// LDS: 8 chunks/operand of 1KB; chunk c = [kseg(4)][row16][8 f16] -> flat l*16B.
// MODE 0: epilogue bias + LoRA, scatter fp16 to Qh/Kh/Vh [bh][n][64]
// MODE 1: epilogue bias, f32 out [m][768]
template<int MODE>
__global__ __launch_bounds__(256)
void gemm_h(const _Float16* __restrict__ A, const _Float16* __restrict__ Bw,
            const float* __restrict__ bias, const float* __restrict__ XA,
            const float* __restrict__ qB, const float* __restrict__ kB,
            _Float16* __restrict__ Oq, _Float16* __restrict__ Ok, _Float16* __restrict__ Ov,
            float* __restrict__ Co) {
    __shared__ __align__(16) _Float16 As[8 * 512];
    __shared__ __align__(16) _Float16 Bs[8 * 512];
    __shared__ __align__(16) float XAs[128 * 16];
    const int t = threadIdx.x;
    const int w = t >> 6, l = t & 63;
    const int l15 = l & 15, lg = l >> 4;
    const int wm = w >> 1, wn = w & 1;
    const int n0 = blockIdx.x * 128, m0 = blockIdx.y * 128;

    if (MODE == 0) {  // stage XA tile for epilogue
        *(float4*)&XAs[t * 8]     = *(const float4*)&XA[m0 * 16 + t * 8];
        *(float4*)&XAs[t * 8 + 4] = *(const float4*)&XA[m0 * 16 + t * 8 + 4];
    }

    const int c0 = 2 * w, c1 = 2 * w + 1;
    const _Float16* gA0 = A  + (size_t)(m0 + c0 * 16 + l15) * 768 + lg * 8;
    const _Float16* gA1 = A  + (size_t)(m0 + c1 * 16 + l15) * 768 + lg * 8;
    const _Float16* gB0 = Bw + (size_t)(n0 + c0 * 16 + l15) * 768 + lg * 8;
    const _Float16* gB1 = Bw + (size_t)(n0 + c1 * 16 + l15) * 768 + lg * 8;

    f32x4 acc[4][4];
#pragma unroll
    for (int i = 0; i < 4; ++i)
#pragma unroll
        for (int j = 0; j < 4; ++j) acc[i][j] = 0.f;

    for (int s = 0; s < 24; ++s) {
        glds16(gA0, &As[c0 * 512]); glds16(gA1, &As[c1 * 512]);
        glds16(gB0, &Bs[c0 * 512]); glds16(gB1, &Bs[c1 * 512]);
        gA0 += 32; gA1 += 32; gB0 += 32; gB1 += 32;
        __syncthreads();
        half8 a[4], b[4];
#pragma unroll
        for (int mi = 0; mi < 4; ++mi) a[mi] = *(const half8*)&As[(wm * 4 + mi) * 512 + l * 8];
#pragma unroll
        for (int ni = 0; ni < 4; ++ni) b[ni] = *(const half8*)&Bs[(wn * 4 + ni) * 512 + l * 8];
#pragma unroll
        for (int mi = 0; mi < 4; ++mi)
#pragma unroll
            for (int ni = 0; ni < 4; ++ni)
                acc[mi][ni] = __builtin_amdgcn_mfma_f32_16x16x32_f16(a[mi], b[ni], acc[mi][ni], 0, 0, 0);
        __syncthreads();
    }

    // epilogue: C row = (l>>4)*4+reg, col = l&15 within each 16x16 frag [m89]
    if (MODE == 0) {
#pragma unroll
        for (int mi = 0; mi < 4; ++mi) {
#pragma unroll
            for (int reg = 0; reg < 4; ++reg) {
                const int mrow = wm * 64 + mi * 16 + lg * 4 + reg;
                const int m = m0 + mrow;
                const int b_ = m >> 10, nn = m & 1023;
                float xr[16];
#pragma unroll
                for (int u = 0; u < 4; ++u) {
                    const float4 v = *(const float4*)&XAs[mrow * 16 + u * 4];
                    xr[u * 4 + 0] = v.x; xr[u * 4 + 1] = v.y;
                    xr[u * 4 + 2] = v.z; xr[u * 4 + 3] = v.w;
                }
#pragma unroll
                for (int ni = 0; ni < 4; ++ni) {
                    const int n = n0 + wn * 64 + ni * 16 + l15;
                    float c = acc[mi][ni][reg] + bias[n];
                    const int sel = (n >= 1536) ? 2 : (n >= 768 ? 1 : 0);
                    const int jj = n - sel * 768;
                    if (sel == 0) {
                        const float* bw = qB + jj * 8;
                        float lo = 0.f;
#pragma unroll
                        for (int r = 0; r < 8; ++r) lo += xr[r] * bw[r];
                        c += 0.125f * lo;
                    } else if (sel == 1) {
                        const float* bw = kB + jj * 8;
                        float lo = 0.f;
#pragma unroll
                        for (int r = 0; r < 8; ++r) lo += xr[8 + r] * bw[r];
                        c += 0.125f * lo;
                    }
                    const int h = jj >> 6, d = jj & 63;
                    _Float16* dst = (sel == 0) ? Oq : (sel == 1 ? Ok : Ov);
                    dst[(((size_t)(b_ * 12 + h)) * 1024 + nn) * 64 + d] = (_Float16)c;
                }
            }
        }
    } else {
#pragma unroll
        for (int mi = 0; mi < 4; ++mi)
#pragma unroll
            for (int reg = 0; reg < 4; ++reg) {
                const int m = m0 + wm * 64 + mi * 16 + lg * 4 + reg;
#pragma unroll
                for (int ni = 0; ni < 4; ++ni) {
                    const int n = n0 + wn * 64 + ni * 16 + l15;
                    Co[(size_t)m * 768 + n] = acc[mi][ni][reg] + bias[n];
                }
            }
    }
}

// ---------------- vt_k: Vt[bh][64][1024] = Vh[bh][1024][64]^T ----------------
__global__ __launch_bounds__(256)
void vt_k(const _Float16* __restrict__ Vh, _Float16* __restrict__ Vt) {
    __shared__ __align__(16) _Float16 tile[64][72];
    const int t = threadIdx.x;
    const int nb = blockIdx.x, bh = blockIdx.y;
    {
        const int key = t >> 2, h0 = (t & 3) * 16;
        const size_t src = ((size_t)(bh * 1024 + nb * 64 + key)) * 64 + h0;
        *(half8*)&tile[key][h0]     = *(const half8*)&Vh[src];
        *(half8*)&tile[key][h0 + 8] = *(const half8*)&Vh[src + 8];
    }
    __syncthreads();
    const int hd = t >> 2, k0 = (t & 3) * 16;
    half8 a, b;
#pragma unroll
    for (int j = 0; j < 8; ++j) { a[j] = tile[k0 + j][hd]; b[j] = tile[k0 + 8 + j][hd]; }
    const size_t dst = ((size_t)(bh * 64 + hd)) * 1024 + nb * 64 + k0;
    *(half8*)&Vt[dst]     = a;
    *(half8*)&Vt[dst + 8] = b;
}

// ---------------- attn_h: flash attention, fp16 MFMA ----------------
// block = 256 thr (4 waves), one (bh, 64-row q block). kb tile = 64 keys.
// Wave w owns q rows 16w..16w+15: S = 4 key-frags, O = 4 hd-frags.
__global__ __launch_bounds__(256)
void attn_h(const _Float16* __restrict__ Q, const _Float16* __restrict__ K,
            const _Float16* __restrict__ Vt, _Float16* __restrict__ AO) {
    __shared__ __align__(16) _Float16 Qs[8 * 512];
    __shared__ __align__(16) _Float16 Ks[8 * 512];
    __shared__ __align__(16) _Float16 Vs[8 * 512];
    __shared__ __align__(16) _Float16 Ps[4 * 1024];   // wave-private 16x64
    const int t = threadIdx.x;
    const int w = t >> 6, l = t & 63;
    const int l15 = l & 15, lg = l >> 4;
    const int qb = blockIdx.x, bh = blockIdx.y;
    const _Float16* Qp = Q  + (size_t)bh * 65536;
    const _Float16* Kp = K  + (size_t)bh * 65536;
    const _Float16* Vp = Vt + (size_t)bh * 65536;     // [64][1024]
    const int c0 = 2 * w, c1 = 2 * w + 1;

    glds16(Qp + (size_t)(qb * 64 + (c0 >> 1) * 16 + l15) * 64 + (c0 & 1) * 32 + lg * 8, &Qs[c0 * 512]);
    glds16(Qp + (size_t)(qb * 64 + (c1 >> 1) * 16 + l15) * 64 + (c1 & 1) * 32 + lg * 8, &Qs[c1 * 512]);
    __syncthreads();
    half8 qf[2];
    qf[0] = *(const half8*)&Qs[(w * 2 + 0) * 512 + l * 8];
    qf[1] = *(const half8*)&Qs[(w * 2 + 1) * 512 + l * 8];

    f32x4 o[4];
#pragma unroll
    for (int fj = 0; fj < 4; ++fj) o[fj] = 0.f;
    float mrun[4] = {-1e30f, -1e30f, -1e30f, -1e30f};
    float lrun[4] = {0.f, 0.f, 0.f, 0.f};

    for (int kb = 0; kb < 16; ++kb) {
        glds16(Kp + (size_t)(kb * 64 + (c0 >> 1) * 16 + l15) * 64 + (c0 & 1) * 32 + lg * 8, &Ks[c0 * 512]);
        glds16(Kp + (size_t)(kb * 64 + (c1 >> 1) * 16 + l15) * 64 + (c1 & 1) * 32 + lg * 8, &Ks[c1 * 512]);
        glds16(Vp + (size_t)((c0 >> 1) * 16 + l15) * 1024 + kb * 64 + (c0 & 1) * 32 + lg * 8, &Vs[c0 * 512]);
        glds16(Vp + (size_t)((c1 >> 1) * 16 + l15) * 1024 + kb * 64 + (c1 & 1) * 32 + lg * 8, &Vs[c1 * 512]);
        __syncthreads();

        f32x4 s[4];
#pragma unroll
        for (int nj = 0; nj < 4; ++nj) s[nj] = 0.f;
#pragma unroll
        for (int nj = 0; nj < 4; ++nj)
#pragma unroll
            for (int h = 0; h < 2; ++h)
                s[nj] = __builtin_amdgcn_mfma_f32_16x16x32_f16(
                    qf[h], *(const half8*)&Ks[(nj * 2 + h) * 512 + l * 8], s[nj], 0, 0, 0);

        float p[4][4], al[4];
#pragma unroll
        for (int reg = 0; reg < 4; ++reg) {
            const float s0 = s[0][reg] * 0.125f, s1 = s[1][reg] * 0.125f;
            const float s2 = s[2][reg] * 0.125f, s3 = s[3][reg] * 0.125f;
            float mx = fmaxf(fmaxf(s0, s1), fmaxf(s2, s3));
            mx = fmaxf(mx, __shfl_xor(mx, 1));
            mx = fmaxf(mx, __shfl_xor(mx, 2));
            mx = fmaxf(mx, __shfl_xor(mx, 4));
            mx = fmaxf(mx, __shfl_xor(mx, 8));
            const float mn = fmaxf(mrun[reg], mx);
            al[reg] = __expf(mrun[reg] - mn);
            mrun[reg] = mn;
            const float p0 = __expf(s0 - mn), p1 = __expf(s1 - mn);
            const float p2 = __expf(s2 - mn), p3 = __expf(s3 - mn);
            float rs = p0 + p1 + p2 + p3;
            rs += __shfl_xor(rs, 1); rs += __shfl_xor(rs, 2);
            rs += __shfl_xor(rs, 4); rs += __shfl_xor(rs, 8);
            lrun[reg] = lrun[reg] * al[reg] + rs;
            p[reg][0] = p0; p[reg][1] = p1; p[reg][2] = p2; p[reg][3] = p3;
        }

#pragma unroll
        for (int reg = 0; reg < 4; ++reg)
#pragma unroll
            for (int nj = 0; nj < 4; ++nj) {
                const int key = l15 + 16 * nj;
                Ps[w * 1024 + (key >> 5) * 512 + ((key & 31) >> 3) * 128 + (lg * 4 + reg) * 8 + (key & 7)]
                    = (_Float16)p[reg][nj];
            }

        half8 pf[2];
        pf[0] = *(const half8*)&Ps[w * 1024 + 0 * 512 + l * 8];
        pf[1] = *(const half8*)&Ps[w * 1024 + 1 * 512 + l * 8];
#pragma unroll
        for (int fj = 0; fj < 4; ++fj) {
#pragma unroll
            for (int reg = 0; reg < 4; ++reg) o[fj][reg] *= al[reg];
#pragma unroll
            for (int kh = 0; kh < 2; ++kh)
                o[fj] = __builtin_amdgcn_mfma_f32_16x16x32_f16(
                    pf[kh], *(const half8*)&Vs[(fj * 2 + kh) * 512 + l * 8], o[fj], 0, 0, 0);
        }
        __syncthreads();   // all PV reads done before next-kb restage
    }

    const int b_ = bh / 12, h = bh % 12;
#pragma unroll
    for (int reg = 0; reg < 4; ++reg) {
        const float inv = 1.f / lrun[reg];
        const int tok = qb * 64 + w * 16 + lg * 4 + reg;
        const size_t base = ((size_t)(b_ * 1024 + tok)) * 768 + h * 64;
#pragma unroll
        for (int fj = 0; fj < 4; ++fj)
            AO[base + fj * 16 + l15] = (_Float16)(o[fj][reg] * inv);
    }
}

// ---------------- launcher ----------------
extern "C" void kernel_launch(void* const* d_in, const int* in_sizes, int n_in,
                              void* d_out, int out_size, void* d_ws, size_t ws_size,
                              hipStream_t stream) {
    (void)in_sizes; (void)n_in; (void)out_size; (void)ws_size;
    const float* x      = (const float*)d_in[0];
    const float* qkv_w  = (const float*)d_in[1];
    const float* qkv_b  = (const float*)d_in[2];
    const float* q_bw   = (const float*)d_in[3];
    const float* q_A    = (const float*)d_in[5];
    const float* q_B    = (const float*)d_in[6];
    const float* k_bw   = (const float*)d_in[7];
    const float* k_A    = (const float*)d_in[9];
    const float* k_B    = (const float*)d_in[10];
    const float* proj_w = (const float*)d_in[11];
    const float* proj_b = (const float*)d_in[12];
    const float* q_bb   = (const float*)d_in[4];
    const float* k_bb   = (const float*)d_in[8];
    float* out = (float*)d_out;
    char*  ws  = (char*)d_ws;

    _Float16* Wh = (_Float16*)(ws + OFF_WH);
    _Float16* Ph = (_Float16*)(ws + OFF_PH);
    float*    bc = (float*)(ws + OFF_BC);
    float*    XA = (float*)(ws + OFF_XA);
    _Float16* Xh = (_Float16*)(ws + OFF_XH);
    _Float16* Qh = (_Float16*)(ws + OFF_QH);
    _Float16* Kh = (_Float16*)(ws + OFF_KH);
    _Float16* Vh = (_Float16*)(ws + OFF_VH);
    _Float16* Vt = (_Float16*)(ws + OFF_VT);
    _Float16* AO = (_Float16*)(ws + OFF_AO);

    prep<<<dim3(9225), dim3(256), 0, stream>>>(qkv_w, qkv_b, q_bw, q_bb, k_bw, k_bb, proj_w, Wh, Ph, bc);
    lora_xa<<<dim3(4096), dim3(256), 0, stream>>>(x, q_A, k_A, XA, Xh);
    gemm_h<0><<<dim3(18, 32), dim3(256), 0, stream>>>(Xh, Wh, bc, XA, q_B, k_B, Qh, Kh, Vh, nullptr);
    vt_k<<<dim3(16, 48), dim3(256), 0, stream>>>(Vh, Vt);
    attn_h<<<dim3(16, 48), dim3(256), 0, stream>>>(Qh, Kh, Vt, AO);
    gemm_h<1><<<dim3(6, 32), dim3(256), 0, stream>>>(AO, Ph, proj_b, nullptr, nullptr, nullptr,
                                                     nullptr, nullptr, nullptr, out);
}

// Round 3
// 128.790 us; speedup vs baseline: 5.1683x; 1.3580x over previous
//
#include <hip/hip_runtime.h>
#include <hip/hip_bf16.h>

// LoRA MHSA fwd, fp16-MFMA, 2-phase pipelined. B=4,N=1024,D=768,H=12,hd=64,r=8
//
// LoRA + bias folded into the QKV GEMM K-dim (K=800):
//   Xext[4096][800] = [fp16(x) | fp16(x@qA.T) | fp16(x@kA.T) | 1.0 | 0*15]
//   Wext[2304][800] = [fold(qkv_w) | 0.125*qB (q rows) | 0.125*kB (k rows) | bias | 0*15]
// gemm_h<128,128,0>: QKV = Xext@Wext.T -> Qh,Kh,Vh fp16 [bh][n][64]   (25 K-steps)
// vt_k             : Vt[bh][64][1024] = Vh^T
// attn_h           : flash attn, 2-phase K/V prefetch, Q in regs
// gemm_h<64,128,1> : out = AO@Ph.T + proj_b (f32)

typedef _Float16 half8 __attribute__((ext_vector_type(8)));
typedef float f32x4 __attribute__((ext_vector_type(4)));

typedef __attribute__((address_space(3))) unsigned int lds_u32;
typedef __attribute__((address_space(1))) const unsigned int glob_u32;

__device__ __forceinline__ void glds16(const void* g, void* l) {
    __builtin_amdgcn_global_load_lds((glob_u32*)g, (lds_u32*)l, 16, 0, 0);
}

// ---- ws layout (byte offsets) ----
constexpr size_t OFF_WX = 0;                                // 2304*800 f16
constexpr size_t OFF_PH = OFF_WX + (size_t)2304*800*2;      // 768*768 f16
constexpr size_t OFF_XE = OFF_PH + (size_t)768*768*2;       // 4096*800 f16
constexpr size_t OFF_QH = OFF_XE + (size_t)4096*800*2;      // 48*1024*64 f16 each:
constexpr size_t OFF_KH = OFF_QH + (size_t)48*1024*64*2;
constexpr size_t OFF_VH = OFF_KH + (size_t)48*1024*64*2;
constexpr size_t OFF_VT = OFF_VH + (size_t)48*1024*64*2;
constexpr size_t OFF_AO = OFF_VT + (size_t)48*1024*64*2;    // 4096*768 f16

// ---------------- prep: build Wext (fold base, LoRA-B cols, bias col) + Ph ----------------
__global__ __launch_bounds__(256)
void prep(const float* __restrict__ qkv_w, const float* __restrict__ qkv_b,
          const float* __restrict__ qw, const float* __restrict__ qbias,
          const float* __restrict__ kw, const float* __restrict__ kbias,
          const float* __restrict__ proj_w, const float* __restrict__ qB,
          const float* __restrict__ kB,
          _Float16* __restrict__ Wx, _Float16* __restrict__ Ph) {
    const int t = threadIdx.x, bb = blockIdx.x;
    if (bb < 2304) {
        const int n = bb;
        const float* wsrc = qkv_w + (size_t)n * 768;
        const float* fold = (n < 768) ? (qw + (size_t)n * 768)
                          : (n < 1536 ? (kw + (size_t)(n - 768) * 768) : nullptr);
        _Float16* dst = Wx + (size_t)n * 800;
#pragma unroll
        for (int i = 0; i < 3; ++i) {
            const int c = t + i * 256;
            float v = wsrc[c];
            if (fold) v += fold[c];
            dst[c] = (_Float16)v;
        }
        if (t < 32) {
            float v = 0.f;
            if (t < 8)       { if (n < 768) v = 0.125f * qB[n * 8 + t]; }
            else if (t < 16) { if (n >= 768 && n < 1536) v = 0.125f * kB[(size_t)(n - 768) * 8 + (t - 8)]; }
            else if (t == 16) v = qkv_b[n] + (n < 768 ? qbias[n] : (n < 1536 ? kbias[n - 768] : 0.f));
            dst[768 + t] = (_Float16)v;
        }
    } else {
        const size_t idx = ((size_t)(bb - 2304) * 256 + t) * 4;   // 576 blocks cover 768*768
        const float4 v = *(const float4*)(proj_w + idx);
        _Float16* d = Ph + idx;
        d[0] = (_Float16)v.x; d[1] = (_Float16)v.y;
        d[2] = (_Float16)v.z; d[3] = (_Float16)v.w;
    }
}

// ---------------- lora_xa: Xext row = [fp16(x) | x@qA.T | x@kA.T | 1 | 0] ----------------
__global__ __launch_bounds__(256)
void lora_xa(const float* __restrict__ x, const float* __restrict__ qA,
             const float* __restrict__ kA, _Float16* __restrict__ Xe) {
    __shared__ float xs[768];
    const int m = blockIdx.x, t = threadIdx.x;
    const float* xr = x + (size_t)m * 768;
    _Float16* dst = Xe + (size_t)m * 800;
#pragma unroll
    for (int i = 0; i < 3; ++i) {
        const int c = t + i * 256;
        const float v = xr[c];
        xs[c] = v;
        dst[c] = (_Float16)v;
    }
    __syncthreads();
    const int j = t >> 4, l = t & 15;
    const float* Arow = (j < 8) ? (qA + j * 768) : (kA + (j - 8) * 768);
    float acc = 0.f;
    for (int k = l; k < 768; k += 16) acc += xs[k] * Arow[k];
    acc += __shfl_xor(acc, 1); acc += __shfl_xor(acc, 2);
    acc += __shfl_xor(acc, 4); acc += __shfl_xor(acc, 8);
    if (l == 0) dst[768 + j] = (_Float16)acc;
    if (t >= 240) dst[784 + (t - 240)] = (t == 240) ? (_Float16)1.f : (_Float16)0.f;
}

// ---------------- 2-phase fp16 MFMA GEMM: C = A @ Bw.T ----------------
// 4 waves (2x2); wave tile (BM/2)x(BN/2); 16x16x32 frags; BK=32; double-buffered LDS.
// LDS chunk c (16 rows x 32 k): flat [lane][8 f16]; lane l -> row c*16+(l&15), k (l>>4)*8.
// MODE 0: scatter fp16 to Oq/Ok/Ov [bh][n][64] (LoRA+bias already in K-dim)
// MODE 1: Co[m][768] = acc + bias[n] (f32)
template<int BM, int BN, int MODE>
__global__ __launch_bounds__(256)
void gemm_h(const _Float16* __restrict__ A, const _Float16* __restrict__ Bw,
            const int lda, const int ldb, const int nsteps,
            const float* __restrict__ bias,
            _Float16* __restrict__ Oq, _Float16* __restrict__ Ok, _Float16* __restrict__ Ov,
            float* __restrict__ Co) {
    constexpr int CA = BM / 16, CB = BN / 16;   // 16-row chunks per tile
    constexpr int MI = BM / 32, NI = BN / 32;   // frags per wave
    __shared__ __align__(16) _Float16 As[2][BM * 32];
    __shared__ __align__(16) _Float16 Bs[2][BN * 32];
    const int t = threadIdx.x;
    const int w = t >> 6, l = t & 63;
    const int l15 = l & 15, lg = l >> 4;
    const int wm = w >> 1, wn = w & 1;

    // XCD-aware bijective swizzle (nwg % 8 == 0 for all our grids)
    const int gx = gridDim.x;
    int lin = blockIdx.y * gx + blockIdx.x;
    lin = (lin & 7) * ((gx * gridDim.y) >> 3) + (lin >> 3);
    const int n0 = (lin % gx) * BN, m0 = (lin / gx) * BM;

    const _Float16* gA[CA / 4];
    const _Float16* gB[CB / 4];
#pragma unroll
    for (int i = 0; i < CA / 4; ++i)
        gA[i] = A + (size_t)(m0 + (w * (CA / 4) + i) * 16 + l15) * lda + lg * 8;
#pragma unroll
    for (int i = 0; i < CB / 4; ++i)
        gB[i] = Bw + (size_t)(n0 + (w * (CB / 4) + i) * 16 + l15) * ldb + lg * 8;

    f32x4 acc[MI][NI];
#pragma unroll
    for (int mi = 0; mi < MI; ++mi)
#pragma unroll
        for (int ni = 0; ni < NI; ++ni) acc[mi][ni] = 0.f;

    // prologue stage tile 0
#pragma unroll
    for (int i = 0; i < CA / 4; ++i) { glds16(gA[i], &As[0][(w * (CA / 4) + i) * 512]); gA[i] += 32; }
#pragma unroll
    for (int i = 0; i < CB / 4; ++i) { glds16(gB[i], &Bs[0][(w * (CB / 4) + i) * 512]); gB[i] += 32; }
    __syncthreads();

    for (int s = 0; s < nsteps; ++s) {
        const int cur = s & 1;
        if (s + 1 < nsteps) {   // prefetch next tile into other buffer BEFORE compute
#pragma unroll
            for (int i = 0; i < CA / 4; ++i) { glds16(gA[i], &As[cur ^ 1][(w * (CA / 4) + i) * 512]); gA[i] += 32; }
#pragma unroll
            for (int i = 0; i < CB / 4; ++i) { glds16(gB[i], &Bs[cur ^ 1][(w * (CB / 4) + i) * 512]); gB[i] += 32; }
        }
        half8 a[MI], b[NI];
#pragma unroll
        for (int mi = 0; mi < MI; ++mi) a[mi] = *(const half8*)&As[cur][(wm * MI + mi) * 512 + l * 8];
#pragma unroll
        for (int ni = 0; ni < NI; ++ni) b[ni] = *(const half8*)&Bs[cur][(wn * NI + ni) * 512 + l * 8];
#pragma unroll
        for (int mi = 0; mi < MI; ++mi)
#pragma unroll
            for (int ni = 0; ni < NI; ++ni)
                acc[mi][ni] = __builtin_amdgcn_mfma_f32_16x16x32_f16(a[mi], b[ni], acc[mi][ni], 0, 0, 0);
        __syncthreads();        // drains prefetch (vmcnt) + all waves done reading cur
    }

    if (MODE == 0) {
#pragma unroll
        for (int mi = 0; mi < MI; ++mi)
#pragma unroll
            for (int reg = 0; reg < 4; ++reg) {
                const int m = m0 + wm * (BM / 2) + mi * 16 + lg * 4 + reg;
                const int b_ = m >> 10, nn = m & 1023;
#pragma unroll
                for (int ni = 0; ni < NI; ++ni) {
                    const int n = n0 + wn * (BN / 2) + ni * 16 + l15;
                    const int sel = (n >= 1536) ? 2 : (n >= 768 ? 1 : 0);
                    const int jj = n - sel * 768;
                    const int h = jj >> 6, d = jj & 63;
                    _Float16* dst = (sel == 0) ? Oq : (sel == 1 ? Ok : Ov);
                    dst[(((size_t)(b_ * 12 + h)) * 1024 + nn) * 64 + d] = (_Float16)acc[mi][ni][reg];
                }
            }
    } else {
#pragma unroll
        for (int mi = 0; mi < MI; ++mi)
#pragma unroll
            for (int reg = 0; reg < 4; ++reg) {
                const int m = m0 + wm * (BM / 2) + mi * 16 + lg * 4 + reg;
#pragma unroll
                for (int ni = 0; ni < NI; ++ni) {
                    const int n = n0 + wn * (BN / 2) + ni * 16 + l15;
                    Co[(size_t)m * 768 + n] = acc[mi][ni][reg] + bias[n];
                }
            }
    }
}

// ---------------- vt_k: Vt[bh][64][1024] = Vh[bh][1024][64]^T ----------------
__global__ __launch_bounds__(256)
void vt_k(const _Float16* __restrict__ Vh, _Float16* __restrict__ Vt) {
    __shared__ __align__(16) _Float16 tile[64][72];
    const int t = threadIdx.x;
    const int nb = blockIdx.x, bh = blockIdx.y;
    {
        const int key = t >> 2, h0 = (t & 3) * 16;
        const size_t src = ((size_t)(bh * 1024 + nb * 64 + key)) * 64 + h0;
        *(half8*)&tile[key][h0]     = *(const half8*)&Vh[src];
        *(half8*)&tile[key][h0 + 8] = *(const half8*)&Vh[src + 8];
    }
    __syncthreads();
    const int hd = t >> 2, k0 = (t & 3) * 16;
    half8 a, b;
#pragma unroll
    for (int j = 0; j < 8; ++j) { a[j] = tile[k0 + j][hd]; b[j] = tile[k0 + 8 + j][hd]; }
    const size_t dst = ((size_t)(bh * 64 + hd)) * 1024 + nb * 64 + k0;
    *(half8*)&Vt[dst]     = a;
    *(half8*)&Vt[dst + 8] = b;
}

// ---------------- attn_h: flash attention, 2-phase K/V prefetch ----------------
__global__ __launch_bounds__(256)
void attn_h(const _Float16* __restrict__ Q, const _Float16* __restrict__ K,
            const _Float16* __restrict__ Vt, _Float16* __restrict__ AO) {
    __shared__ __align__(16) _Float16 Ks[2][4096];
    __shared__ __align__(16) _Float16 Vs[2][4096];
    __shared__ __align__(16) _Float16 Ps[4][1024];
    const int t = threadIdx.x;
    const int w = t >> 6, l = t & 63;
    const int l15 = l & 15, lg = l >> 4;

    int lin = blockIdx.y * 16 + blockIdx.x;          // grid 16 x 48 = 768
    lin = (lin & 7) * 96 + (lin >> 3);               // XCD swizzle
    const int qb = lin & 15, bh = lin >> 4;

    const _Float16* Qp = Q  + (size_t)bh * 65536;
    const _Float16* Kp = K  + (size_t)bh * 65536;
    const _Float16* Vp = Vt + (size_t)bh * 65536;    // [64][1024]

    // prologue: stage tile 0; Q direct-to-reg
#pragma unroll
    for (int hf = 0; hf < 2; ++hf) {
        glds16(Kp + (size_t)(w * 16 + l15) * 64 + hf * 32 + lg * 8, &Ks[0][(w * 2 + hf) * 512]);
        glds16(Vp + (size_t)(w * 16 + l15) * 1024 + hf * 32 + lg * 8, &Vs[0][(w * 2 + hf) * 512]);
    }
    half8 qf[2];
#pragma unroll
    for (int hf = 0; hf < 2; ++hf)
        qf[hf] = *(const half8*)&Qp[(size_t)(qb * 64 + w * 16 + l15) * 64 + hf * 32 + lg * 8];

    f32x4 o[4];
#pragma unroll
    for (int fj = 0; fj < 4; ++fj) o[fj] = 0.f;
    float mrun[4] = {-1e30f, -1e30f, -1e30f, -1e30f};
    float lrun[4] = {0.f, 0.f, 0.f, 0.f};
    __syncthreads();

    for (int kb = 0; kb < 16; ++kb) {
        const int cur = kb & 1;
        if (kb < 15) {  // prefetch next K/V tile before compute
#pragma unroll
            for (int hf = 0; hf < 2; ++hf) {
                glds16(Kp + (size_t)((kb + 1) * 64 + w * 16 + l15) * 64 + hf * 32 + lg * 8,
                       &Ks[cur ^ 1][(w * 2 + hf) * 512]);
                glds16(Vp + (size_t)(w * 16 + l15) * 1024 + (kb + 1) * 64 + hf * 32 + lg * 8,
                       &Vs[cur ^ 1][(w * 2 + hf) * 512]);
            }
        }

        f32x4 s[4];
#pragma unroll
        for (int nj = 0; nj < 4; ++nj) s[nj] = 0.f;
#pragma unroll
        for (int nj = 0; nj < 4; ++nj)
#pragma unroll
            for (int hf = 0; hf < 2; ++hf)
                s[nj] = __builtin_amdgcn_mfma_f32_16x16x32_f16(
                    qf[hf], *(const half8*)&Ks[cur][(nj * 2 + hf) * 512 + l * 8], s[nj], 0, 0, 0);

        float p[4][4], al[4];
#pragma unroll
        for (int reg = 0; reg < 4; ++reg) {
            const float s0 = s[0][reg] * 0.125f, s1 = s[1][reg] * 0.125f;
            const float s2 = s[2][reg] * 0.125f, s3 = s[3][reg] * 0.125f;
            float mx = fmaxf(fmaxf(s0, s1), fmaxf(s2, s3));
            mx = fmaxf(mx, __shfl_xor(mx, 1));
            mx = fmaxf(mx, __shfl_xor(mx, 2));
            mx = fmaxf(mx, __shfl_xor(mx, 4));
            mx = fmaxf(mx, __shfl_xor(mx, 8));
            const float mn = fmaxf(mrun[reg], mx);
            al[reg] = __expf(mrun[reg] - mn);
            mrun[reg] = mn;
            const float p0 = __expf(s0 - mn), p1 = __expf(s1 - mn);
            const float p2 = __expf(s2 - mn), p3 = __expf(s3 - mn);
            float rs = p0 + p1 + p2 + p3;
            rs += __shfl_xor(rs, 1); rs += __shfl_xor(rs, 2);
            rs += __shfl_xor(rs, 4); rs += __shfl_xor(rs, 8);
            lrun[reg] = lrun[reg] * al[reg] + rs;
            p[reg][0] = p0; p[reg][1] = p1; p[reg][2] = p2; p[reg][3] = p3;
        }

        // P -> wave-private LDS in PV A-frag layout, then read fragments
#pragma unroll
        for (int reg = 0; reg < 4; ++reg)
#pragma unroll
            for (int nj = 0; nj < 4; ++nj) {
                const int key = l15 + 16 * nj;
                Ps[w][(key >> 5) * 512 + ((key & 31) >> 3) * 128 + (lg * 4 + reg) * 8 + (key & 7)]
                    = (_Float16)p[reg][nj];
            }
        half8 pf[2];
        pf[0] = *(const half8*)&Ps[w][l * 8];
        pf[1] = *(const half8*)&Ps[w][512 + l * 8];

#pragma unroll
        for (int fj = 0; fj < 4; ++fj) {
#pragma unroll
            for (int reg = 0; reg < 4; ++reg) o[fj][reg] *= al[reg];
#pragma unroll
            for (int kh = 0; kh < 2; ++kh)
                o[fj] = __builtin_amdgcn_mfma_f32_16x16x32_f16(
                    pf[kh], *(const half8*)&Vs[cur][(fj * 2 + kh) * 512 + l * 8], o[fj], 0, 0, 0);
        }
        __syncthreads();   // prefetch landed + all reads of cur done
    }

    const int b_ = bh / 12, h = bh % 12;
#pragma unroll
    for (int reg = 0; reg < 4; ++reg) {
        const float inv = 1.f / lrun[reg];
        const int tok = qb * 64 + w * 16 + lg * 4 + reg;
        const size_t base = ((size_t)(b_ * 1024 + tok)) * 768 + h * 64;
#pragma unroll
        for (int fj = 0; fj < 4; ++fj)
            AO[base + fj * 16 + l15] = (_Float16)(o[fj][reg] * inv);
    }
}

// ---------------- launcher ----------------
extern "C" void kernel_launch(void* const* d_in, const int* in_sizes, int n_in,
                              void* d_out, int out_size, void* d_ws, size_t ws_size,
                              hipStream_t stream) {
    (void)in_sizes; (void)n_in; (void)out_size; (void)ws_size;
    const float* x      = (const float*)d_in[0];
    const float* qkv_w  = (const float*)d_in[1];
    const float* qkv_b  = (const float*)d_in[2];
    const float* q_bw   = (const float*)d_in[3];
    const float* q_bb   = (const float*)d_in[4];
    const float* q_A    = (const float*)d_in[5];
    const float* q_B    = (const float*)d_in[6];
    const float* k_bw   = (const float*)d_in[7];
    const float* k_bb   = (const float*)d_in[8];
    const float* k_A    = (const float*)d_in[9];
    const float* k_B    = (const float*)d_in[10];
    const float* proj_w = (const float*)d_in[11];
    const float* proj_b = (const float*)d_in[12];
    float* out = (float*)d_out;
    char*  ws  = (char*)d_ws;

    _Float16* Wx = (_Float16*)(ws + OFF_WX);
    _Float16* Ph = (_Float16*)(ws + OFF_PH);
    _Float16* Xe = (_Float16*)(ws + OFF_XE);
    _Float16* Qh = (_Float16*)(ws + OFF_QH);
    _Float16* Kh = (_Float16*)(ws + OFF_KH);
    _Float16* Vh = (_Float16*)(ws + OFF_VH);
    _Float16* Vt = (_Float16*)(ws + OFF_VT);
    _Float16* AO = (_Float16*)(ws + OFF_AO);

    prep<<<dim3(2880), dim3(256), 0, stream>>>(qkv_w, qkv_b, q_bw, q_bb, k_bw, k_bb,
                                               proj_w, q_B, k_B, Wx, Ph);
    lora_xa<<<dim3(4096), dim3(256), 0, stream>>>(x, q_A, k_A, Xe);
    gemm_h<128, 128, 0><<<dim3(18, 32), dim3(256), 0, stream>>>(
        Xe, Wx, 800, 800, 25, nullptr, Qh, Kh, Vh, nullptr);
    vt_k<<<dim3(16, 48), dim3(256), 0, stream>>>(Vh, Vt);
    attn_h<<<dim3(16, 48), dim3(256), 0, stream>>>(Qh, Kh, Vt, AO);
    gemm_h<64, 128, 1><<<dim3(6, 64), dim3(256), 0, stream>>>(
        AO, Ph, 768, 768, 24, proj_b, nullptr, nullptr, nullptr, out);
}

// Round 5
// 115.588 us; speedup vs baseline: 5.7586x; 1.1142x over previous
//
#include <hip/hip_runtime.h>
#include <hip/hip_bf16.h>

// LoRA MHSA fwd, fp16-MFMA. B=4,N=1024,D=768,H=12,hd=64,r=8
//
// LoRA + bias folded into QKV GEMM K-dim (K=800); softmax scale 0.125*log2e
// folded into the Q rows of Wext (attention uses raw exp2, no max, deferred sum).
//   Xext[4096][800] = [fp16(x) | x@qA.T | x@kA.T | 1 | 0*15]
//   Wext[2304][800] = [fold(qkv_w) | lora-B | bias | 0*15], q rows pre-scaled
// gemm_h<128,128,0>: QKV -> Qh,Kh,Vh fp16 [bh][n][64]
// vt_k             : Vt[bh][64][1024] = Vh^T
// attn2            : flash attn, 2 waves x 32 rows, swapped QK^T, no-max exp2
// gemm_h<64,128,1> : out = AO@Ph.T + proj_b (f32)

typedef _Float16 half8 __attribute__((ext_vector_type(8)));
typedef float f32x4 __attribute__((ext_vector_type(4)));

typedef __attribute__((address_space(3))) unsigned int lds_u32;
typedef __attribute__((address_space(1))) const unsigned int glob_u32;

__device__ __forceinline__ void glds16(const void* g, void* l) {
    __builtin_amdgcn_global_load_lds((glob_u32*)g, (lds_u32*)l, 16, 0, 0);
}

__device__ __forceinline__ float pk2f16(float a, float b) {   // pack 2 f32 -> 2 f16 (RTZ), as f32 bits
    return __builtin_bit_cast(float, __builtin_amdgcn_cvt_pkrtz(a, b));
}

// 0.125 (softmax scale) * log2(e)
#define SMSCALE 0.18033688011112042f

// ---- ws layout (byte offsets) ----
constexpr size_t OFF_WX = 0;                                // 2304*800 f16
constexpr size_t OFF_PH = OFF_WX + (size_t)2304*800*2;      // 768*768 f16
constexpr size_t OFF_XE = OFF_PH + (size_t)768*768*2;       // 4096*800 f16
constexpr size_t OFF_QH = OFF_XE + (size_t)4096*800*2;
constexpr size_t OFF_KH = OFF_QH + (size_t)48*1024*64*2;
constexpr size_t OFF_VH = OFF_KH + (size_t)48*1024*64*2;
constexpr size_t OFF_VT = OFF_VH + (size_t)48*1024*64*2;
constexpr size_t OFF_AO = OFF_VT + (size_t)48*1024*64*2;    // 4096*768 f16

// ---------------- prep: build Wext + Ph ----------------
__global__ __launch_bounds__(256)
void prep(const float* __restrict__ qkv_w, const float* __restrict__ qkv_b,
          const float* __restrict__ qw, const float* __restrict__ qbias,
          const float* __restrict__ kw, const float* __restrict__ kbias,
          const float* __restrict__ proj_w, const float* __restrict__ qB,
          const float* __restrict__ kB,
          _Float16* __restrict__ Wx, _Float16* __restrict__ Ph) {
    const int t = threadIdx.x, bb = blockIdx.x;
    if (bb < 2304) {
        const int n = bb;
        const float rs = (n < 768) ? SMSCALE : 1.0f;   // fold softmax scale into Q rows
        const float* wsrc = qkv_w + (size_t)n * 768;
        const float* fold = (n < 768) ? (qw + (size_t)n * 768)
                          : (n < 1536 ? (kw + (size_t)(n - 768) * 768) : nullptr);
        _Float16* dst = Wx + (size_t)n * 800;
#pragma unroll
        for (int i = 0; i < 3; ++i) {
            const int c = t + i * 256;
            float v = wsrc[c];
            if (fold) v += fold[c];
            dst[c] = (_Float16)(v * rs);
        }
        if (t < 32) {
            float v = 0.f;
            if (t < 8)       { if (n < 768) v = rs * 0.125f * qB[n * 8 + t]; }
            else if (t < 16) { if (n >= 768 && n < 1536) v = 0.125f * kB[(size_t)(n - 768) * 8 + (t - 8)]; }
            else if (t == 16) v = rs * (qkv_b[n] + (n < 768 ? qbias[n] : (n < 1536 ? kbias[n - 768] : 0.f)));
            dst[768 + t] = (_Float16)v;
        }
    } else {
        const size_t idx = ((size_t)(bb - 2304) * 256 + t) * 4;
        const float4 v = *(const float4*)(proj_w + idx);
        _Float16* d = Ph + idx;
        d[0] = (_Float16)v.x; d[1] = (_Float16)v.y;
        d[2] = (_Float16)v.z; d[3] = (_Float16)v.w;
    }
}

// ---------------- lora_xa: Xext row = [fp16(x) | x@qA.T | x@kA.T | 1 | 0] ----------------
__global__ __launch_bounds__(256)
void lora_xa(const float* __restrict__ x, const float* __restrict__ qA,
             const float* __restrict__ kA, _Float16* __restrict__ Xe) {
    __shared__ float xs[768];
    const int m = blockIdx.x, t = threadIdx.x;
    const float* xr = x + (size_t)m * 768;
    _Float16* dst = Xe + (size_t)m * 800;
#pragma unroll
    for (int i = 0; i < 3; ++i) {
        const int c = t + i * 256;
        const float v = xr[c];
        xs[c] = v;
        dst[c] = (_Float16)v;
    }
    __syncthreads();
    const int j = t >> 4, l = t & 15;
    const float* Arow = (j < 8) ? (qA + j * 768) : (kA + (j - 8) * 768);
    float acc = 0.f;
    for (int k = l; k < 768; k += 16) acc += xs[k] * Arow[k];
    acc += __shfl_xor(acc, 1); acc += __shfl_xor(acc, 2);
    acc += __shfl_xor(acc, 4); acc += __shfl_xor(acc, 8);
    if (l == 0) dst[768 + j] = (_Float16)acc;
    if (t >= 240) dst[784 + (t - 240)] = (t == 240) ? (_Float16)1.f : (_Float16)0.f;
}

// ---------------- 2-phase fp16 MFMA GEMM: C = A @ Bw.T ----------------
template<int BM, int BN, int MODE>
__global__ __launch_bounds__(256)
void gemm_h(const _Float16* __restrict__ A, const _Float16* __restrict__ Bw,
            const int lda, const int ldb, const int nsteps,
            const float* __restrict__ bias,
            _Float16* __restrict__ Oq, _Float16* __restrict__ Ok, _Float16* __restrict__ Ov,
            float* __restrict__ Co) {
    constexpr int CA = BM / 16, CB = BN / 16;
    constexpr int MI = BM / 32, NI = BN / 32;
    __shared__ __align__(16) _Float16 As[2][BM * 32];
    __shared__ __align__(16) _Float16 Bs[2][BN * 32];
    const int t = threadIdx.x;
    const int w = t >> 6, l = t & 63;
    const int l15 = l & 15, lg = l >> 4;
    const int wm = w >> 1, wn = w & 1;

    const int gx = gridDim.x;
    int lin = blockIdx.y * gx + blockIdx.x;
    lin = (lin & 7) * ((gx * gridDim.y) >> 3) + (lin >> 3);
    const int n0 = (lin % gx) * BN, m0 = (lin / gx) * BM;

    const _Float16* gA[CA / 4];
    const _Float16* gB[CB / 4];
#pragma unroll
    for (int i = 0; i < CA / 4; ++i)
        gA[i] = A + (size_t)(m0 + (w * (CA / 4) + i) * 16 + l15) * lda + lg * 8;
#pragma unroll
    for (int i = 0; i < CB / 4; ++i)
        gB[i] = Bw + (size_t)(n0 + (w * (CB / 4) + i) * 16 + l15) * ldb + lg * 8;

    f32x4 acc[MI][NI];
#pragma unroll
    for (int mi = 0; mi < MI; ++mi)
#pragma unroll
        for (int ni = 0; ni < NI; ++ni) acc[mi][ni] = 0.f;

#pragma unroll
    for (int i = 0; i < CA / 4; ++i) { glds16(gA[i], &As[0][(w * (CA / 4) + i) * 512]); gA[i] += 32; }
#pragma unroll
    for (int i = 0; i < CB / 4; ++i) { glds16(gB[i], &Bs[0][(w * (CB / 4) + i) * 512]); gB[i] += 32; }
    __syncthreads();

    for (int s = 0; s < nsteps; ++s) {
        const int cur = s & 1;
        if (s + 1 < nsteps) {
#pragma unroll
            for (int i = 0; i < CA / 4; ++i) { glds16(gA[i], &As[cur ^ 1][(w * (CA / 4) + i) * 512]); gA[i] += 32; }
#pragma unroll
            for (int i = 0; i < CB / 4; ++i) { glds16(gB[i], &Bs[cur ^ 1][(w * (CB / 4) + i) * 512]); gB[i] += 32; }
        }
        half8 a[MI], b[NI];
#pragma unroll
        for (int mi = 0; mi < MI; ++mi) a[mi] = *(const half8*)&As[cur][(wm * MI + mi) * 512 + l * 8];
#pragma unroll
        for (int ni = 0; ni < NI; ++ni) b[ni] = *(const half8*)&Bs[cur][(wn * NI + ni) * 512 + l * 8];
#pragma unroll
        for (int mi = 0; mi < MI; ++mi)
#pragma unroll
            for (int ni = 0; ni < NI; ++ni)
                acc[mi][ni] = __builtin_amdgcn_mfma_f32_16x16x32_f16(a[mi], b[ni], acc[mi][ni], 0, 0, 0);
        __syncthreads();
    }

    if (MODE == 0) {
#pragma unroll
        for (int mi = 0; mi < MI; ++mi)
#pragma unroll
            for (int reg = 0; reg < 4; ++reg) {
                const int m = m0 + wm * (BM / 2) + mi * 16 + lg * 4 + reg;
                const int b_ = m >> 10, nn = m & 1023;
#pragma unroll
                for (int ni = 0; ni < NI; ++ni) {
                    const int n = n0 + wn * (BN / 2) + ni * 16 + l15;
                    const int sel = (n >= 1536) ? 2 : (n >= 768 ? 1 : 0);
                    const int jj = n - sel * 768;
                    const int h = jj >> 6, d = jj & 63;
                    _Float16* dst = (sel == 0) ? Oq : (sel == 1 ? Ok : Ov);
                    dst[(((size_t)(b_ * 12 + h)) * 1024 + nn) * 64 + d] = (_Float16)acc[mi][ni][reg];
                }
            }
    } else {
#pragma unroll
        for (int mi = 0; mi < MI; ++mi)
#pragma unroll
            for (int reg = 0; reg < 4; ++reg) {
                const int m = m0 + wm * (BM / 2) + mi * 16 + lg * 4 + reg;
#pragma unroll
                for (int ni = 0; ni < NI; ++ni) {
                    const int n = n0 + wn * (BN / 2) + ni * 16 + l15;
                    Co[(size_t)m * 768 + n] = acc[mi][ni][reg] + bias[n];
                }
            }
    }
}

// ---------------- vt_k: Vt[bh][64][1024] = Vh[bh][1024][64]^T ----------------
__global__ __launch_bounds__(256)
void vt_k(const _Float16* __restrict__ Vh, _Float16* __restrict__ Vt) {
    __shared__ __align__(16) _Float16 tile[64][72];
    const int t = threadIdx.x;
    const int nb = blockIdx.x, bh = blockIdx.y;
    {
        const int key = t >> 2, h0 = (t & 3) * 16;
        const size_t src = ((size_t)(bh * 1024 + nb * 64 + key)) * 64 + h0;
        *(half8*)&tile[key][h0]     = *(const half8*)&Vh[src];
        *(half8*)&tile[key][h0 + 8] = *(const half8*)&Vh[src + 8];
    }
    __syncthreads();
    const int hd = t >> 2, k0 = (t & 3) * 16;
    half8 a, b;
#pragma unroll
    for (int j = 0; j < 8; ++j) { a[j] = tile[k0 + j][hd]; b[j] = tile[k0 + 8 + j][hd]; }
    const size_t dst = ((size_t)(bh * 64 + hd)) * 1024 + nb * 64 + k0;
    *(half8*)&Vt[dst]     = a;
    *(half8*)&Vt[dst + 8] = b;
}

// ---------------- attn2: flash attn, 2 waves x 32 q-rows, swapped QK, no-max exp2 ----------------
// Wave w owns q rows [w*32, w*32+32). Per kb tile (64 keys):
//   s[mi][nj] = mfma(Kfrag, Qfrag) -> lane holds S^T[key=16nj+4lg+reg][qrow=16mi+l15]
//   p = exp2(s) (scale pre-folded into Q); per-lane partial sums; packed b64 P-writes;
//   PV: o[mi][fj] += mfma(Pfrag, Vfrag). Normalize by total sum at the end.
__global__ __launch_bounds__(128)
void attn2(const _Float16* __restrict__ Q, const _Float16* __restrict__ K,
           const _Float16* __restrict__ Vt, _Float16* __restrict__ AO) {
    __shared__ __align__(16) _Float16 Ks[2][4096];
    __shared__ __align__(16) _Float16 Vs[2][4096];
    __shared__ __align__(16) _Float16 Ps[2][2048];
    __shared__ float sums[2][32];
    const int t = threadIdx.x;
    const int w = t >> 6, l = t & 63;
    const int l15 = l & 15, lg = l >> 4;

    int lin = blockIdx.y * 16 + blockIdx.x;          // 768 blocks
    lin = (lin & 7) * 96 + (lin >> 3);               // XCD swizzle
    const int qb = lin & 15, bh = lin >> 4;

    const _Float16* Qp = Q  + (size_t)bh * 65536;
    const _Float16* Kp = K  + (size_t)bh * 65536;
    const _Float16* Vp = Vt + (size_t)bh * 65536;    // [64][1024]

    // stage kb=0 (each wave stages 4 of 8 chunks per operand)
#pragma unroll
    for (int i = 0; i < 4; ++i) {
        const int c = w * 4 + i;
        glds16(Kp + (size_t)((c >> 1) * 16 + l15) * 64 + (c & 1) * 32 + lg * 8, &Ks[0][c * 512]);
        glds16(Vp + (size_t)((c >> 1) * 16 + l15) * 1024 + (c & 1) * 32 + lg * 8, &Vs[0][c * 512]);
    }
    // Q direct-to-reg (B-operand frags)
    half8 qf[2][2];
#pragma unroll
    for (int mi = 0; mi < 2; ++mi)
#pragma unroll
        for (int kh = 0; kh < 2; ++kh)
            qf[mi][kh] = *(const half8*)&Qp[(size_t)(qb * 64 + w * 32 + mi * 16 + l15) * 64 + kh * 32 + lg * 8];

    f32x4 o[2][4];
#pragma unroll
    for (int mi = 0; mi < 2; ++mi)
#pragma unroll
        for (int fj = 0; fj < 4; ++fj) o[mi][fj] = 0.f;
    float lsum[2] = {0.f, 0.f};
    __syncthreads();

    for (int kb = 0; kb < 16; ++kb) {
        const int cur = kb & 1;
        if (kb < 15) {   // prefetch next tile
#pragma unroll
            for (int i = 0; i < 4; ++i) {
                const int c = w * 4 + i;
                glds16(Kp + (size_t)((kb + 1) * 64 + (c >> 1) * 16 + l15) * 64 + (c & 1) * 32 + lg * 8,
                       &Ks[cur ^ 1][c * 512]);
                glds16(Vp + (size_t)((c >> 1) * 16 + l15) * 1024 + (kb + 1) * 64 + (c & 1) * 32 + lg * 8,
                       &Vs[cur ^ 1][c * 512]);
            }
        }

        half8 kreg[8];
#pragma unroll
        for (int c = 0; c < 8; ++c) kreg[c] = *(const half8*)&Ks[cur][c * 512 + l * 8];

#pragma unroll
        for (int mi = 0; mi < 2; ++mi) {
            f32x4 s[4];
#pragma unroll
            for (int nj = 0; nj < 4; ++nj) s[nj] = 0.f;
#pragma unroll
            for (int nj = 0; nj < 4; ++nj)
#pragma unroll
                for (int kh = 0; kh < 2; ++kh)
                    s[nj] = __builtin_amdgcn_mfma_f32_16x16x32_f16(kreg[nj * 2 + kh], qf[mi][kh], s[nj], 0, 0, 0);
            float ls = 0.f;
#pragma unroll
            for (int nj = 0; nj < 4; ++nj) {
                const float p0 = __builtin_amdgcn_exp2f(s[nj][0]);
                const float p1 = __builtin_amdgcn_exp2f(s[nj][1]);
                const float p2 = __builtin_amdgcn_exp2f(s[nj][2]);
                const float p3 = __builtin_amdgcn_exp2f(s[nj][3]);
                ls += (p0 + p1) + (p2 + p3);
                float2 pk;
                pk.x = pk2f16(p0, p1);
                pk.y = pk2f16(p2, p3);
                const int off = (mi * 2 + (nj >> 1)) * 512 + (2 * (nj & 1) + (lg >> 1)) * 128
                              + l15 * 8 + 4 * (lg & 1);
                *(float2*)&Ps[w][off] = pk;
            }
            lsum[mi] += ls;
        }

        half8 pf[2][2];
#pragma unroll
        for (int mi = 0; mi < 2; ++mi)
#pragma unroll
            for (int kh = 0; kh < 2; ++kh)
                pf[mi][kh] = *(const half8*)&Ps[w][(mi * 2 + kh) * 512 + l * 8];

#pragma unroll
        for (int fj = 0; fj < 4; ++fj)
#pragma unroll
            for (int kh = 0; kh < 2; ++kh) {
                const half8 vf = *(const half8*)&Vs[cur][(fj * 2 + kh) * 512 + l * 8];
#pragma unroll
                for (int mi = 0; mi < 2; ++mi)
                    o[mi][fj] = __builtin_amdgcn_mfma_f32_16x16x32_f16(pf[mi][kh], vf, o[mi][fj], 0, 0, 0);
            }
        __syncthreads();   // prefetch landed + all reads of cur done
    }

    // total sums per q-row (reduce across lg lanes), bounce via LDS for C-layout access
#pragma unroll
    for (int mi = 0; mi < 2; ++mi) {
        float tot = lsum[mi];
        tot += __shfl_xor(tot, 16);
        tot += __shfl_xor(tot, 32);
        if (lg == 0) sums[w][mi * 16 + l15] = tot;
    }
    __builtin_amdgcn_wave_barrier();

    const int b_ = bh / 12, h = bh % 12;
#pragma unroll
    for (int mi = 0; mi < 2; ++mi)
#pragma unroll
        for (int reg = 0; reg < 4; ++reg) {
            const float inv = 1.f / sums[w][mi * 16 + lg * 4 + reg];
            const int tok = qb * 64 + w * 32 + mi * 16 + lg * 4 + reg;
            const size_t base = ((size_t)(b_ * 1024 + tok)) * 768 + h * 64;
#pragma unroll
            for (int fj = 0; fj < 4; ++fj)
                AO[base + fj * 16 + l15] = (_Float16)(o[mi][fj][reg] * inv);
        }
}

// ---------------- launcher ----------------
extern "C" void kernel_launch(void* const* d_in, const int* in_sizes, int n_in,
                              void* d_out, int out_size, void* d_ws, size_t ws_size,
                              hipStream_t stream) {
    (void)in_sizes; (void)n_in; (void)out_size; (void)ws_size;
    const float* x      = (const float*)d_in[0];
    const float* qkv_w  = (const float*)d_in[1];
    const float* qkv_b  = (const float*)d_in[2];
    const float* q_bw   = (const float*)d_in[3];
    const float* q_bb   = (const float*)d_in[4];
    const float* q_A    = (const float*)d_in[5];
    const float* q_B    = (const float*)d_in[6];
    const float* k_bw   = (const float*)d_in[7];
    const float* k_bb   = (const float*)d_in[8];
    const float* k_A    = (const float*)d_in[9];
    const float* k_B    = (const float*)d_in[10];
    const float* proj_w = (const float*)d_in[11];
    const float* proj_b = (const float*)d_in[12];
    float* out = (float*)d_out;
    char*  ws  = (char*)d_ws;

    _Float16* Wx = (_Float16*)(ws + OFF_WX);
    _Float16* Ph = (_Float16*)(ws + OFF_PH);
    _Float16* Xe = (_Float16*)(ws + OFF_XE);
    _Float16* Qh = (_Float16*)(ws + OFF_QH);
    _Float16* Kh = (_Float16*)(ws + OFF_KH);
    _Float16* Vh = (_Float16*)(ws + OFF_VH);
    _Float16* Vt = (_Float16*)(ws + OFF_VT);
    _Float16* AO = (_Float16*)(ws + OFF_AO);

    prep<<<dim3(2880), dim3(256), 0, stream>>>(qkv_w, qkv_b, q_bw, q_bb, k_bw, k_bb,
                                               proj_w, q_B, k_B, Wx, Ph);
    lora_xa<<<dim3(4096), dim3(256), 0, stream>>>(x, q_A, k_A, Xe);
    gemm_h<128, 128, 0><<<dim3(18, 32), dim3(256), 0, stream>>>(
        Xe, Wx, 800, 800, 25, nullptr, Qh, Kh, Vh, nullptr);
    vt_k<<<dim3(16, 48), dim3(256), 0, stream>>>(Vh, Vt);
    attn2<<<dim3(16, 48), dim3(128), 0, stream>>>(Qh, Kh, Vt, AO);
    gemm_h<64, 128, 1><<<dim3(6, 64), dim3(256), 0, stream>>>(
        AO, Ph, 768, 768, 24, proj_b, nullptr, nullptr, nullptr, out);
}